// Round 9
// baseline (288.772 us; speedup 1.0000x reference)
//
#include <hip/hip_runtime.h>
#include <math.h>

#define F_NUM 8
#define N_AT 2048
#define E_EDGE 32768
#define FE (F_NUM*E_EDGE)   // 262144 base edges
#define FN (F_NUM*N_AT)     // 16384 atoms
#define CAP 72              // per-atom incidence capacity (avg 32, Poisson)
#define PI_F 3.14159265358979f

#if defined(__has_builtin)
#if __has_builtin(__builtin_amdgcn_fdot2)
#define HAS_FDOT2 1
#endif
#endif

typedef _Float16 h2 __attribute__((ext_vector_type(2)));

__device__ __forceinline__ unsigned short f2b(float x) {
    unsigned int u = __float_as_uint(x);
    u += 0x8000u;
    return (unsigned short)(u >> 16);
}
__device__ __forceinline__ float blo(unsigned int u) { return __uint_as_float(u << 16); }
__device__ __forceinline__ float bhi(unsigned int u) { return __uint_as_float(u & 0xffff0000u); }
__device__ __forceinline__ float b2f(unsigned short u) { return __uint_as_float((unsigned)u << 16); }

__device__ __forceinline__ unsigned f2h(float x) {
    union { _Float16 h; unsigned short u; } cv;
    cv.h = (_Float16)x;
    return (unsigned)cv.u;
}
__device__ __forceinline__ h2 u2h2(unsigned u) {
    union { unsigned u; h2 h; } cv;
    cv.u = u;
    return cv.h;
}
// dot of 8 f16-packed values (uint4) with 8 f16 weights (4x half2), f32 accumulate
__device__ __forceinline__ float dot8h(uint4 q, const h2* w) {
#ifdef HAS_FDOT2
    float a = __builtin_amdgcn_fdot2(u2h2(q.x), w[0], 0.f, false);
    a = __builtin_amdgcn_fdot2(u2h2(q.y), w[1], a, false);
    a = __builtin_amdgcn_fdot2(u2h2(q.z), w[2], a, false);
    a = __builtin_amdgcn_fdot2(u2h2(q.w), w[3], a, false);
    return a;
#else
    h2 a0 = u2h2(q.x), a1 = u2h2(q.y), a2 = u2h2(q.z), a3 = u2h2(q.w);
    return (float)a0.x*(float)w[0].x + (float)a0.y*(float)w[0].y
         + (float)a1.x*(float)w[1].x + (float)a1.y*(float)w[1].y
         + (float)a2.x*(float)w[2].x + (float)a2.y*(float)w[2].y
         + (float)a3.x*(float)w[3].x + (float)a3.y*(float)w[3].y;
#endif
}
// build half2 weight pairs for channel c from Wrad layout [8][C*4]
__device__ __forceinline__ void prep_wr(const float* __restrict__ Wrad_l, int c, h2* wr) {
#pragma unroll
    for (int bb = 0; bb < 4; bb++) {
        h2 t;
        t.x = (_Float16)Wrad_l[(2*bb)   * 128 + c * 4];
        t.y = (_Float16)Wrad_l[(2*bb+1) * 128 + c * 4];
        wr[bb] = t;
    }
}

// nbq encoding: (u << 3) | (sign << 2) | type    sign=1 means this visit's unit points away (negate)

// ---------------- edges: geometry, f16 dbasis+unit (edge order), f16 basis + nbq/kinc (incidence order) ----------------
__global__ __launch_bounds__(256) void k_edges(
    const float* __restrict__ pos, const int* __restrict__ eidx,
    const float* __restrict__ cell, const int* __restrict__ co_p,
    const int* __restrict__ at,
    uint4* __restrict__ dbq, float4* __restrict__ unit,
    int* __restrict__ cnt, int* __restrict__ nbq, int* __restrict__ kinc,
    uint4* __restrict__ binc)
{
    int k = blockIdx.x * 256 + threadIdx.x;
    if (k >= FE) return;
    int f = k >> 15;
    int e = k & (E_EDGE - 1);
    int a = eidx[f * 2 * E_EDGE + e] + f * N_AT;
    int b = eidx[f * 2 * E_EDGE + E_EDGE + e] + f * N_AT;
    int ta = at[a], tb = at[b];
    float co = (float)co_p[0];

    float vec[3];
#pragma unroll
    for (int d = 0; d < 3; d++) {
        float v  = pos[3 * b + d] - pos[3 * a + d];
        float cl = cell[3 * f + d];
        float sh = cl * ((v < -co ? 1.f : 0.f) - (v > co ? 1.f : 0.f));
        vec[d] = v + sh;
    }
    float r2   = vec[0]*vec[0] + vec[1]*vec[1] + vec[2]*vec[2] + 1e-12f;
    float r    = sqrtf(r2);
    float rinv = 1.f / r;
    unit[k] = make_float4(vec[0]*rinv, vec[1]*rinv, vec[2]*rinv, 0.f);

    float x = r * (1.f / 6.f);           // R_MAX = 6
    float env = 0.f, denv = 0.f;
    if (x < 1.f) {
        float x2 = x*x, x3 = x2*x, x5 = x2*x3, x6 = x5*x, x7 = x6*x, x8 = x7*x;
        env  = 1.f - 28.f*x6 + 48.f*x7 - 21.f*x8;
        denv = -168.f*x5 + 336.f*x6 - 168.f*x7;
    }
    float s1, c1;
    sincosf(PI_F * x, &s1, &c1);
    float sn = s1, cn = c1;
    const float C0 = 0.57735026919f;     // sqrt(2/6)
    float bs[8], db[8];
#pragma unroll
    for (int n = 1; n <= 8; n++) {
        float kn  = (float)n * PI_F * (1.f / 6.f);
        float bes = C0 * sn * rinv;
        bs[n-1] = bes * env;
        db[n-1] = C0 * rinv * (kn * cn - sn * rinv) * env + bes * denv * (1.f / 6.f);
        float sn2 = sn * c1 + cn * s1;
        float cn2 = cn * c1 - sn * s1;
        sn = sn2; cn = cn2;
    }
    uint4 B, D;
    B.x = f2h(bs[0]) | (f2h(bs[1]) << 16);
    B.y = f2h(bs[2]) | (f2h(bs[3]) << 16);
    B.z = f2h(bs[4]) | (f2h(bs[5]) << 16);
    B.w = f2h(bs[6]) | (f2h(bs[7]) << 16);
    D.x = f2h(db[0]) | (f2h(db[1]) << 16);
    D.y = f2h(db[2]) | (f2h(db[3]) << 16);
    D.z = f2h(db[4]) | (f2h(db[5]) << 16);
    D.w = f2h(db[6]) | (f2h(db[7]) << 16);
    dbq[k] = D;

    int sa = atomicAdd(&cnt[a], 1);
    if (sa < CAP) {
        int ia = a * CAP + sa;
        nbq[ia] = (b << 3) | tb;           // + direction
        kinc[ia] = k;
        binc[ia] = B;
    }
    int sb = atomicAdd(&cnt[b], 1);
    if (sb < CAP) {
        int ib = b * CAP + sb;
        nbq[ib] = (a << 3) | 4 | ta;       // - direction
        kinc[ib] = k;
        binc[ib] = B;
    }
}

// ---------------- g2[c] = sum_d w_out[d] * Wmix2[c,d] ----------------
__global__ void k_g2(const float* __restrict__ w_out, const float* __restrict__ Wmix2, float* __restrict__ g2)
{
    int c = threadIdx.x;
    float acc = 0.f;
#pragma unroll
    for (int d = 0; d < 32; d++) acc += w_out[d] * Wmix2[c * 32 + d];
    g2[c] = acc;
}

// ---------------- forward layer: 2 atoms/block, 4 groups/atom ----------------
template<bool L0>
__global__ __launch_bounds__(256, 8) void k_L(
    const unsigned short* __restrict__ slq, const float* __restrict__ W_embed,
    unsigned short* __restrict__ soq,
    const int* __restrict__ cnt, const int* __restrict__ nbq, const uint4* __restrict__ binc,
    const float* __restrict__ Wrad_l, const float* __restrict__ Wmix_l,
    const int* __restrict__ at)
{
    __shared__ float wmix[1024];
    __shared__ float Ash[2][4][32];
    __shared__ float We[128];
    int t = threadIdx.x;
    for (int i = t; i < 1024; i += 256) wmix[i] = Wmix_l[i];
    if (L0 && t < 128) We[t] = W_embed[t];
    int g = t >> 5, c = t & 31;
    int al = g >> 2, q = g & 3;
    int n = blockIdx.x * 2 + al;
    h2 wr[4];
    prep_wr(Wrad_l, c, wr);
    __syncthreads();

    int cn = min(cnt[n], CAP);
    int base = n * CAP;
    int j  = base + ((cn * q) >> 2);
    int j1 = base + ((cn * (q + 1)) >> 2);
    float A = 0.f;
    for (; j + 3 < j1; j += 4) {
        int n0 = nbq[j], n1 = nbq[j+1], n2 = nbq[j+2], n3 = nbq[j+3];
        uint4 b0 = binc[j], b1 = binc[j+1], b2 = binc[j+2], b3 = binc[j+3];
        float sv0, sv1, sv2, sv3;
        if (L0) {
            sv0 = We[(n0 & 3) * 32 + c];
            sv1 = We[(n1 & 3) * 32 + c];
            sv2 = We[(n2 & 3) * 32 + c];
            sv3 = We[(n3 & 3) * 32 + c];
        } else {
            sv0 = b2f(slq[(n0 >> 3) * 32 + c]);
            sv1 = b2f(slq[(n1 >> 3) * 32 + c]);
            sv2 = b2f(slq[(n2 >> 3) * 32 + c]);
            sv3 = b2f(slq[(n3 >> 3) * 32 + c]);
        }
        A += dot8h(b0, wr) * sv0 + dot8h(b1, wr) * sv1
           + dot8h(b2, wr) * sv2 + dot8h(b3, wr) * sv3;
    }
    for (; j < j1; ++j) {
        int n0 = nbq[j];
        uint4 b0 = binc[j];
        float sv0 = L0 ? We[(n0 & 3) * 32 + c] : b2f(slq[(n0 >> 3) * 32 + c]);
        A += dot8h(b0, wr) * sv0;
    }
    Ash[al][q][c] = A;
    __syncthreads();
    if (q == 0) {
        float acc = 0.f;
#pragma unroll 8
        for (int cc = 0; cc < 32; cc++) {
            float Av = Ash[al][0][cc] + Ash[al][1][cc] + Ash[al][2][cc] + Ash[al][3][cc];
            acc += Av * wmix[cc * 32 + c];
        }
        float base_s = L0 ? We[at[n] * 32 + c] : b2f(slq[n * 32 + c]);
        soq[n * 32 + c] = f2b(base_s + acc);
    }
}

// ---------------- layer 2 fused: energy partial + barS2 + barA1(bf16) ----------------
__global__ __launch_bounds__(256, 8) void k_L2E(
    const unsigned short* __restrict__ s2q,
    const int* __restrict__ cnt, const int* __restrict__ nbq, const uint4* __restrict__ binc,
    const float* __restrict__ Wrad2, const float* __restrict__ Wmix1,
    const float* __restrict__ w_out, const float* __restrict__ g2,
    float* __restrict__ barS2, unsigned short* __restrict__ ba1q, float* __restrict__ epart)
{
    __shared__ float wmixT[1056];   // Wmix1 transposed, stride 33
    __shared__ float Ash[2][4][32];
    __shared__ float Ssh[2][4][32];
    __shared__ float Bsh[2][32];
    int t = threadIdx.x;
    for (int i = t; i < 1024; i += 256) wmixT[(i & 31) * 33 + (i >> 5)] = Wmix1[i];
    int g = t >> 5, c = t & 31;
    int al = g >> 2, q = g & 3;
    int n = blockIdx.x * 2 + al;
    h2 wr[4];
    prep_wr(Wrad2, c, wr);
    __syncthreads();

    int cn = min(cnt[n], CAP);
    int base = n * CAP;
    int j  = base + ((cn * q) >> 2);
    int j1 = base + ((cn * (q + 1)) >> 2);
    float A = 0.f, S = 0.f;
    for (; j + 3 < j1; j += 4) {
        int n0 = nbq[j], n1 = nbq[j+1], n2 = nbq[j+2], n3 = nbq[j+3];
        uint4 b0 = binc[j], b1 = binc[j+1], b2 = binc[j+2], b3 = binc[j+3];
        float r0 = dot8h(b0, wr), r1 = dot8h(b1, wr), r2 = dot8h(b2, wr), r3 = dot8h(b3, wr);
        A += r0 * b2f(s2q[(n0 >> 3) * 32 + c]) + r1 * b2f(s2q[(n1 >> 3) * 32 + c])
           + r2 * b2f(s2q[(n2 >> 3) * 32 + c]) + r3 * b2f(s2q[(n3 >> 3) * 32 + c]);
        S += r0 + r1 + r2 + r3;
    }
    for (; j < j1; ++j) {
        int n0 = nbq[j];
        float r0 = dot8h(binc[j], wr);
        A += r0 * b2f(s2q[(n0 >> 3) * 32 + c]);
        S += r0;
    }
    Ash[al][q][c] = A;
    Ssh[al][q][c] = S;
    __syncthreads();
    if (q == 0) {
        float At = Ash[al][0][c] + Ash[al][1][c] + Ash[al][2][c] + Ash[al][3][c];
        float St = Ssh[al][0][c] + Ssh[al][1][c] + Ssh[al][2][c] + Ssh[al][3][c];
        float woc = w_out[c], g2c = g2[c];
        float s2n = b2f(s2q[n * 32 + c]);
        float te = s2n * woc + At * g2c;
#pragma unroll
        for (int o = 1; o <= 16; o <<= 1) te += __shfl_xor(te, o, 32);
        if (c == 0) epart[n] = te;
        float bs2 = woc + g2c * St;
        barS2[n * 32 + c] = bs2;
        Bsh[al][c] = bs2;
        float acc = 0.f;
#pragma unroll 8
        for (int d = 0; d < 32; d++) acc += Bsh[al][d] * wmixT[d * 33 + c];
        ba1q[n * 32 + c] = f2b(acc);
    }
}

// ---------------- backward l=1 fused: barS1 -> barA0 -> pk ----------------
// pk layout: x = s1 | s2<<16 ; y = ba0 | ba1<<16
__global__ __launch_bounds__(256, 8) void k_B1F(
    const unsigned short* __restrict__ ba1q, const float* __restrict__ barS2,
    const unsigned short* __restrict__ s1q, const unsigned short* __restrict__ s2q,
    const int* __restrict__ cnt, const int* __restrict__ nbq, const uint4* __restrict__ binc,
    const float* __restrict__ Wrad1, const float* __restrict__ Wmix0,
    uint2* __restrict__ pk)
{
    __shared__ float wmixT[1056];   // Wmix0 transposed, stride 33
    __shared__ float Ash[2][4][32];
    __shared__ float Bsh[2][32];
    int t = threadIdx.x;
    for (int i = t; i < 1024; i += 256) wmixT[(i & 31) * 33 + (i >> 5)] = Wmix0[i];
    int g = t >> 5, c = t & 31;
    int al = g >> 2, q = g & 3;
    int n = blockIdx.x * 2 + al;
    h2 wr[4];
    prep_wr(Wrad1, c, wr);
    __syncthreads();

    int cn = min(cnt[n], CAP);
    int base = n * CAP;
    int j  = base + ((cn * q) >> 2);
    int j1 = base + ((cn * (q + 1)) >> 2);
    float A = 0.f;
    for (; j + 3 < j1; j += 4) {
        int n0 = nbq[j], n1 = nbq[j+1], n2 = nbq[j+2], n3 = nbq[j+3];
        uint4 b0 = binc[j], b1 = binc[j+1], b2 = binc[j+2], b3 = binc[j+3];
        A += dot8h(b0, wr) * b2f(ba1q[(n0 >> 3) * 32 + c])
           + dot8h(b1, wr) * b2f(ba1q[(n1 >> 3) * 32 + c])
           + dot8h(b2, wr) * b2f(ba1q[(n2 >> 3) * 32 + c])
           + dot8h(b3, wr) * b2f(ba1q[(n3 >> 3) * 32 + c]);
    }
    for (; j < j1; ++j) {
        int n0 = nbq[j];
        A += dot8h(binc[j], wr) * b2f(ba1q[(n0 >> 3) * 32 + c]);
    }
    Ash[al][q][c] = A;
    __syncthreads();
    if (q == 0) {
        float At = Ash[al][0][c] + Ash[al][1][c] + Ash[al][2][c] + Ash[al][3][c];
        int n32c = n * 32 + c;
        float bs1 = barS2[n32c] + At;
        Bsh[al][c] = bs1;
        float acc = 0.f;
#pragma unroll 8
        for (int d = 0; d < 32; d++) acc += Bsh[al][d] * wmixT[d * 33 + c];
        uint2 v;
        v.x = (unsigned)s1q[n32c] | ((unsigned)s2q[n32c] << 16);
        v.y = (unsigned)f2b(acc)  | ((unsigned)ba1q[n32c] << 16);
        pk[n32c] = v;
    }
}

// ---------------- energy reduction: 2048 per frame -> out[f] (plain store) ----------------
__global__ __launch_bounds__(256) void k_ered(const float* __restrict__ epart, float* __restrict__ out)
{
    __shared__ float sm[256];
    int f = blockIdx.x, t = threadIdx.x;
    float a = 0.f;
    for (int i = t; i < N_AT; i += 256) a += epart[f * N_AT + i];
    sm[t] = a;
    __syncthreads();
    for (int s = 128; s; s >>= 1) {
        if (t < s) sm[t] += sm[t + s];
        __syncthreads();
    }
    if (t == 0) out[f] = sm[0];
}

// ---------------- forces, GATHER form: 2 atoms/block, 4 streams/atom, no atomics ----------------
__global__ __launch_bounds__(256, 8) void k_forceG(
    const uint2* __restrict__ pk, const float* __restrict__ g2,
    const uint4* __restrict__ dbq, const float4* __restrict__ unit,
    const int* __restrict__ cnt, const int* __restrict__ nbq, const int* __restrict__ kinc,
    const float* __restrict__ W_rad, const int* __restrict__ at,
    const float* __restrict__ W_embed, float* __restrict__ out)
{
    __shared__ float We[128];
    __shared__ float Fsh[2][4][3];
    int t = threadIdx.x;
    if (t < 128) We[t] = W_embed[t];
    int g = t >> 5, c = t & 31;
    int al = g >> 2, q = g & 3;
    int n = blockIdx.x * 2 + al;
    h2 wr0[4], wr1[4], wr2[4];
    prep_wr(W_rad + 0 * 1024, c, wr0);
    prep_wr(W_rad + 1 * 1024, c, wr1);
    prep_wr(W_rad + 2 * 1024, c, wr2);
    float g2c = g2[c];
    __syncthreads();

    uint2 mq = pk[n * 32 + c];
    float ms1 = blo(mq.x), ms2 = bhi(mq.x);
    float mb0 = blo(mq.y), mb1 = bhi(mq.y);
    float ms0 = We[at[n] * 32 + c];

    float Fx = 0.f, Fy = 0.f, Fz = 0.f;
    int cn = min(cnt[n], CAP);
    int base = n * CAP;
    int j  = base + ((cn * q) >> 2);
    int j1 = base + ((cn * (q + 1)) >> 2);

#define FPROC(JJ)                                                            \
    {                                                                        \
        int nb = nbq[JJ]; int k = kinc[JJ];                                  \
        uint4 d = dbq[k];                                                    \
        float4 uv = unit[k];                                                 \
        uint2 qq = pk[(nb >> 3) * 32 + c];                                   \
        float s0u = We[(nb & 3) * 32 + c];                                   \
        float dR0 = dot8h(d, wr0), dR1 = dot8h(d, wr1), dR2 = dot8h(d, wr2); \
        float term = dR0 * (mb0 * s0u + blo(qq.y) * ms0)                     \
                   + dR1 * (mb1 * blo(qq.x) + bhi(qq.y) * ms1)               \
                   + dR2 * g2c * (bhi(qq.x) + ms2);                          \
        term = (nb & 4) ? -term : term;                                      \
        Fx += term * uv.x; Fy += term * uv.y; Fz += term * uv.z;             \
    }

    for (; j + 3 < j1; j += 4) { FPROC(j) FPROC(j+1) FPROC(j+2) FPROC(j+3) }
    for (; j < j1; ++j) { FPROC(j) }
#undef FPROC

#pragma unroll
    for (int o = 1; o <= 16; o <<= 1) {
        Fx += __shfl_xor(Fx, o, 32);
        Fy += __shfl_xor(Fy, o, 32);
        Fz += __shfl_xor(Fz, o, 32);
    }
    if (c == 0) { Fsh[al][q][0] = Fx; Fsh[al][q][1] = Fy; Fsh[al][q][2] = Fz; }
    __syncthreads();
    if (q == 0 && c < 3) {
        float v = Fsh[al][0][c] + Fsh[al][1][c] + Fsh[al][2][c] + Fsh[al][3][c];
        out[8 + n * 3 + c] = v;
    }
}

extern "C" void kernel_launch(void* const* d_in, const int* in_sizes, int n_in,
                              void* d_out, int out_size, void* d_ws, size_t ws_size,
                              hipStream_t stream)
{
    const float* pos     = (const float*)d_in[0];
    const int*   eidx    = (const int*)  d_in[1];
    const float* cell    = (const float*)d_in[2];
    const int*   at      = (const int*)  d_in[3];
    const float* W_embed = (const float*)d_in[4];
    const float* W_rad   = (const float*)d_in[5];
    const float* W_mix   = (const float*)d_in[6];
    const float* w_out   = (const float*)d_in[7];
    const int*   co      = (const int*)  d_in[8];

    char* p = (char*)d_ws;
    auto carve = [&](size_t bytes) -> char* {
        char* r = p;
        p += (bytes + 255) & ~(size_t)255;
        return r;
    };
    uint4*          dbq    = (uint4*)          carve((size_t)FE * 16);
    float4*         unit   = (float4*)         carve((size_t)FE * 16);
    unsigned short* s1q    = (unsigned short*) carve((size_t)FN * 32 * 2);
    unsigned short* s2q    = (unsigned short*) carve((size_t)FN * 32 * 2);
    unsigned short* ba1q   = (unsigned short*) carve((size_t)FN * 32 * 2);
    float*          barS2  = (float*)          carve((size_t)FN * 32 * 4);
    uint2*          pk     = (uint2*)          carve((size_t)FN * 32 * 8);
    float*          g2     = (float*)          carve(32 * 4);
    float*          epart  = (float*)          carve((size_t)FN * 4);
    int*            cnt    = (int*)            carve((size_t)FN * 4);
    int*            nbq    = (int*)            carve((size_t)FN * CAP * 4);
    int*            kinc   = (int*)            carve((size_t)FN * CAP * 4);
    uint4*          binc   = (uint4*)          carve((size_t)FN * CAP * 16);

    hipMemsetAsync(cnt, 0, (size_t)FN * 4, stream);

    k_edges<<<FE / 256, 256, 0, stream>>>(pos, eidx, cell, co, at, dbq, unit, cnt, nbq, kinc, binc);
    k_g2<<<1, 32, 0, stream>>>(w_out, W_mix + 2 * 1024, g2);

    // forward
    k_L<true><<<FN / 2, 256, 0, stream>>>(nullptr, W_embed, s1q, cnt, nbq, binc,
                                          W_rad + 0 * 1024, W_mix + 0 * 1024, at);
    k_L<false><<<FN / 2, 256, 0, stream>>>(s1q, W_embed, s2q, cnt, nbq, binc,
                                           W_rad + 1 * 1024, W_mix + 1 * 1024, at);
    // layer 2 + energy partials + barS2 + barA1
    k_L2E<<<FN / 2, 256, 0, stream>>>(s2q, cnt, nbq, binc, W_rad + 2 * 1024,
                                      W_mix + 1 * 1024, w_out, g2, barS2, ba1q, epart);
    // backward l=1 + barA0 + pack
    k_B1F<<<FN / 2, 256, 0, stream>>>(ba1q, barS2, s1q, s2q, cnt, nbq, binc,
                                      W_rad + 1 * 1024, W_mix + 0 * 1024, pk);
    // energy reduce (plain stores)
    k_ered<<<F_NUM, 256, 0, stream>>>(epart, (float*)d_out);
    // forces (gather, no atomics)
    k_forceG<<<FN / 2, 256, 0, stream>>>(pk, g2, dbq, unit, cnt, nbq, kinc,
                                         W_rad, at, W_embed, (float*)d_out);
}

// Round 10
// 227.901 us; speedup vs baseline: 1.2671x; 1.2671x over previous
//
#include <hip/hip_runtime.h>
#include <math.h>

#define F_NUM 8
#define N_AT 2048
#define E_EDGE 32768
#define FE (F_NUM*E_EDGE)   // 262144 base edges
#define FN (F_NUM*N_AT)     // 16384 atoms
#define CAP 72              // per-atom incidence capacity (avg 32, Poisson)
#define PI_F 3.14159265358979f

#if defined(__has_builtin)
#if __has_builtin(__builtin_amdgcn_fdot2)
#define HAS_FDOT2 1
#endif
#endif

typedef _Float16 h2 __attribute__((ext_vector_type(2)));

// XCD-aware swizzle: consecutive work chunks land on one XCD (frame-major work)
#define XSWZ(bid, G) (((bid) & 7) * ((G) >> 3) + ((bid) >> 3))

__device__ __forceinline__ unsigned short f2b(float x) {
    unsigned int u = __float_as_uint(x);
    u += 0x8000u;
    return (unsigned short)(u >> 16);
}
__device__ __forceinline__ float blo(unsigned int u) { return __uint_as_float(u << 16); }
__device__ __forceinline__ float bhi(unsigned int u) { return __uint_as_float(u & 0xffff0000u); }
__device__ __forceinline__ float b2f(unsigned short u) { return __uint_as_float((unsigned)u << 16); }

__device__ __forceinline__ unsigned f2h(float x) {
    union { _Float16 h; unsigned short u; } cv;
    cv.h = (_Float16)x;
    return (unsigned)cv.u;
}
__device__ __forceinline__ h2 u2h2(unsigned u) {
    union { unsigned u; h2 h; } cv;
    cv.u = u;
    return cv.h;
}
__device__ __forceinline__ float dot8h(uint4 q, const h2* w) {
#ifdef HAS_FDOT2
    float a = __builtin_amdgcn_fdot2(u2h2(q.x), w[0], 0.f, false);
    a = __builtin_amdgcn_fdot2(u2h2(q.y), w[1], a, false);
    a = __builtin_amdgcn_fdot2(u2h2(q.z), w[2], a, false);
    a = __builtin_amdgcn_fdot2(u2h2(q.w), w[3], a, false);
    return a;
#else
    h2 a0 = u2h2(q.x), a1 = u2h2(q.y), a2 = u2h2(q.z), a3 = u2h2(q.w);
    return (float)a0.x*(float)w[0].x + (float)a0.y*(float)w[0].y
         + (float)a1.x*(float)w[1].x + (float)a1.y*(float)w[1].y
         + (float)a2.x*(float)w[2].x + (float)a2.y*(float)w[2].y
         + (float)a3.x*(float)w[3].x + (float)a3.y*(float)w[3].y;
#endif
}
__device__ __forceinline__ void prep_wr(const float* __restrict__ Wrad_l, int c, h2* wr) {
#pragma unroll
    for (int bb = 0; bb < 4; bb++) {
        h2 t;
        t.x = (_Float16)Wrad_l[(2*bb)   * 128 + c * 4];
        t.y = (_Float16)Wrad_l[(2*bb+1) * 128 + c * 4];
        wr[bb] = t;
    }
}

// Incidence record (32 B, one cache line per write):
//   rec[2j]   = { nb, B.x, B.y, B.z }    nb = (u<<3)|(sign<<2)|type
//   rec[2j+1] = { B.w, 0, 0, 0 }

// ---------------- edges: geometry, f16 dbasis+unit (edge order), AoS incidence records ----------------
__global__ __launch_bounds__(256) void k_edges(
    const float* __restrict__ pos, const int* __restrict__ eidx,
    const float* __restrict__ cell, const int* __restrict__ co_p,
    const int* __restrict__ at,
    uint4* __restrict__ dbq, float4* __restrict__ unit,
    int* __restrict__ cnt, uint4* __restrict__ rec)
{
    int bid = XSWZ(blockIdx.x, FE / 256);
    int k = bid * 256 + threadIdx.x;
    int f = k >> 15;
    int e = k & (E_EDGE - 1);
    int a = eidx[f * 2 * E_EDGE + e] + f * N_AT;
    int b = eidx[f * 2 * E_EDGE + E_EDGE + e] + f * N_AT;
    int ta = at[a], tb = at[b];
    float co = (float)co_p[0];

    float vec[3];
#pragma unroll
    for (int d = 0; d < 3; d++) {
        float v  = pos[3 * b + d] - pos[3 * a + d];
        float cl = cell[3 * f + d];
        float sh = cl * ((v < -co ? 1.f : 0.f) - (v > co ? 1.f : 0.f));
        vec[d] = v + sh;
    }
    float r2   = vec[0]*vec[0] + vec[1]*vec[1] + vec[2]*vec[2] + 1e-12f;
    float r    = sqrtf(r2);
    float rinv = 1.f / r;
    unit[k] = make_float4(vec[0]*rinv, vec[1]*rinv, vec[2]*rinv, 0.f);

    float x = r * (1.f / 6.f);           // R_MAX = 6
    float env = 0.f, denv = 0.f;
    if (x < 1.f) {
        float x2 = x*x, x3 = x2*x, x5 = x2*x3, x6 = x5*x, x7 = x6*x, x8 = x7*x;
        env  = 1.f - 28.f*x6 + 48.f*x7 - 21.f*x8;
        denv = -168.f*x5 + 336.f*x6 - 168.f*x7;
    }
    float s1, c1;
    sincosf(PI_F * x, &s1, &c1);
    float sn = s1, cn = c1;
    const float C0 = 0.57735026919f;     // sqrt(2/6)
    float bs[8], db[8];
#pragma unroll
    for (int n = 1; n <= 8; n++) {
        float kn  = (float)n * PI_F * (1.f / 6.f);
        float bes = C0 * sn * rinv;
        bs[n-1] = bes * env;
        db[n-1] = C0 * rinv * (kn * cn - sn * rinv) * env + bes * denv * (1.f / 6.f);
        float sn2 = sn * c1 + cn * s1;
        float cn2 = cn * c1 - sn * s1;
        sn = sn2; cn = cn2;
    }
    uint4 B, D;
    B.x = f2h(bs[0]) | (f2h(bs[1]) << 16);
    B.y = f2h(bs[2]) | (f2h(bs[3]) << 16);
    B.z = f2h(bs[4]) | (f2h(bs[5]) << 16);
    B.w = f2h(bs[6]) | (f2h(bs[7]) << 16);
    D.x = f2h(db[0]) | (f2h(db[1]) << 16);
    D.y = f2h(db[2]) | (f2h(db[3]) << 16);
    D.z = f2h(db[4]) | (f2h(db[5]) << 16);
    D.w = f2h(db[6]) | (f2h(db[7]) << 16);
    dbq[k] = D;

    int sa = atomicAdd(&cnt[a], 1);
    if (sa < CAP) {
        int ia = 2 * (a * CAP + sa);
        rec[ia]     = make_uint4((unsigned)((b << 3) | tb), B.x, B.y, B.z);
        rec[ia + 1] = make_uint4(B.w, 0, 0, 0);
    }
    int sb = atomicAdd(&cnt[b], 1);
    if (sb < CAP) {
        int ib = 2 * (b * CAP + sb);
        rec[ib]     = make_uint4((unsigned)((a << 3) | 4 | ta), B.x, B.y, B.z);
        rec[ib + 1] = make_uint4(B.w, 0, 0, 0);
    }
}

// ---------------- g2[c] = sum_d w_out[d] * Wmix2[c,d] ----------------
__global__ void k_g2(const float* __restrict__ w_out, const float* __restrict__ Wmix2, float* __restrict__ g2)
{
    int c = threadIdx.x;
    float acc = 0.f;
#pragma unroll
    for (int d = 0; d < 32; d++) acc += w_out[d] * Wmix2[c * 32 + d];
    g2[c] = acc;
}

#define LOADREC(J, NB, B)                                    \
    {                                                        \
        uint4 ra = rec[2*(J)], rb = rec[2*(J)+1];            \
        NB = (int)ra.x;                                      \
        B  = make_uint4(ra.y, ra.z, ra.w, rb.x);             \
    }

// ---------------- forward layer: 2 atoms/block, 4 groups/atom ----------------
template<bool L0>
__global__ __launch_bounds__(256, 8) void k_L(
    const unsigned short* __restrict__ slq, const float* __restrict__ W_embed,
    unsigned short* __restrict__ soq,
    const int* __restrict__ cnt, const uint4* __restrict__ rec,
    const float* __restrict__ Wrad_l, const float* __restrict__ Wmix_l,
    const int* __restrict__ at)
{
    __shared__ float wmix[1024];
    __shared__ float Ash[2][4][32];
    __shared__ float We[128];
    int t = threadIdx.x;
    for (int i = t; i < 1024; i += 256) wmix[i] = Wmix_l[i];
    if (L0 && t < 128) We[t] = W_embed[t];
    int bid = XSWZ(blockIdx.x, FN / 2);
    int g = t >> 5, c = t & 31;
    int al = g >> 2, q = g & 3;
    int n = bid * 2 + al;
    h2 wr[4];
    prep_wr(Wrad_l, c, wr);
    __syncthreads();

    int cn = min(cnt[n], CAP);
    int base = n * CAP;
    int j  = base + ((cn * q) >> 2);
    int j1 = base + ((cn * (q + 1)) >> 2);
    float A = 0.f;
    for (; j + 3 < j1; j += 4) {
        int n0, n1, n2, n3;
        uint4 b0, b1, b2, b3;
        LOADREC(j, n0, b0) LOADREC(j+1, n1, b1) LOADREC(j+2, n2, b2) LOADREC(j+3, n3, b3)
        float sv0, sv1, sv2, sv3;
        if (L0) {
            sv0 = We[(n0 & 3) * 32 + c];
            sv1 = We[(n1 & 3) * 32 + c];
            sv2 = We[(n2 & 3) * 32 + c];
            sv3 = We[(n3 & 3) * 32 + c];
        } else {
            sv0 = b2f(slq[(n0 >> 3) * 32 + c]);
            sv1 = b2f(slq[(n1 >> 3) * 32 + c]);
            sv2 = b2f(slq[(n2 >> 3) * 32 + c]);
            sv3 = b2f(slq[(n3 >> 3) * 32 + c]);
        }
        A += dot8h(b0, wr) * sv0 + dot8h(b1, wr) * sv1
           + dot8h(b2, wr) * sv2 + dot8h(b3, wr) * sv3;
    }
    for (; j < j1; ++j) {
        int n0; uint4 b0;
        LOADREC(j, n0, b0)
        float sv0 = L0 ? We[(n0 & 3) * 32 + c] : b2f(slq[(n0 >> 3) * 32 + c]);
        A += dot8h(b0, wr) * sv0;
    }
    Ash[al][q][c] = A;
    __syncthreads();
    if (q == 0) {
        float acc = 0.f;
#pragma unroll 8
        for (int cc = 0; cc < 32; cc++) {
            float Av = Ash[al][0][cc] + Ash[al][1][cc] + Ash[al][2][cc] + Ash[al][3][cc];
            acc += Av * wmix[cc * 32 + c];
        }
        float base_s = L0 ? We[at[n] * 32 + c] : b2f(slq[n * 32 + c]);
        soq[n * 32 + c] = f2b(base_s + acc);
    }
}

// ---------------- layer 2 fused: energy partial + barS2 + barA1(bf16) ----------------
__global__ __launch_bounds__(256, 8) void k_L2E(
    const unsigned short* __restrict__ s2q,
    const int* __restrict__ cnt, const uint4* __restrict__ rec,
    const float* __restrict__ Wrad2, const float* __restrict__ Wmix1,
    const float* __restrict__ w_out, const float* __restrict__ g2,
    float* __restrict__ barS2, unsigned short* __restrict__ ba1q, float* __restrict__ epart)
{
    __shared__ float wmixT[1056];   // Wmix1 transposed, stride 33
    __shared__ float Ash[2][4][32];
    __shared__ float Ssh[2][4][32];
    __shared__ float Bsh[2][32];
    int t = threadIdx.x;
    for (int i = t; i < 1024; i += 256) wmixT[(i & 31) * 33 + (i >> 5)] = Wmix1[i];
    int bid = XSWZ(blockIdx.x, FN / 2);
    int g = t >> 5, c = t & 31;
    int al = g >> 2, q = g & 3;
    int n = bid * 2 + al;
    h2 wr[4];
    prep_wr(Wrad2, c, wr);
    __syncthreads();

    int cn = min(cnt[n], CAP);
    int base = n * CAP;
    int j  = base + ((cn * q) >> 2);
    int j1 = base + ((cn * (q + 1)) >> 2);
    float A = 0.f, S = 0.f;
    for (; j + 3 < j1; j += 4) {
        int n0, n1, n2, n3;
        uint4 b0, b1, b2, b3;
        LOADREC(j, n0, b0) LOADREC(j+1, n1, b1) LOADREC(j+2, n2, b2) LOADREC(j+3, n3, b3)
        float r0 = dot8h(b0, wr), r1 = dot8h(b1, wr), r2 = dot8h(b2, wr), r3 = dot8h(b3, wr);
        A += r0 * b2f(s2q[(n0 >> 3) * 32 + c]) + r1 * b2f(s2q[(n1 >> 3) * 32 + c])
           + r2 * b2f(s2q[(n2 >> 3) * 32 + c]) + r3 * b2f(s2q[(n3 >> 3) * 32 + c]);
        S += r0 + r1 + r2 + r3;
    }
    for (; j < j1; ++j) {
        int n0; uint4 b0;
        LOADREC(j, n0, b0)
        float r0 = dot8h(b0, wr);
        A += r0 * b2f(s2q[(n0 >> 3) * 32 + c]);
        S += r0;
    }
    Ash[al][q][c] = A;
    Ssh[al][q][c] = S;
    __syncthreads();
    if (q == 0) {
        float At = Ash[al][0][c] + Ash[al][1][c] + Ash[al][2][c] + Ash[al][3][c];
        float St = Ssh[al][0][c] + Ssh[al][1][c] + Ssh[al][2][c] + Ssh[al][3][c];
        float woc = w_out[c], g2c = g2[c];
        float s2n = b2f(s2q[n * 32 + c]);
        float te = s2n * woc + At * g2c;
#pragma unroll
        for (int o = 1; o <= 16; o <<= 1) te += __shfl_xor(te, o, 32);
        if (c == 0) epart[n] = te;
        float bs2 = woc + g2c * St;
        barS2[n * 32 + c] = bs2;
        Bsh[al][c] = bs2;
        float acc = 0.f;
#pragma unroll 8
        for (int d = 0; d < 32; d++) acc += Bsh[al][d] * wmixT[d * 33 + c];
        ba1q[n * 32 + c] = f2b(acc);
    }
}

// ---------------- backward l=1 fused: barS1 -> barA0 -> pk ----------------
// pk layout: x = s1 | s2<<16 ; y = ba0 | ba1<<16
__global__ __launch_bounds__(256, 8) void k_B1F(
    const unsigned short* __restrict__ ba1q, const float* __restrict__ barS2,
    const unsigned short* __restrict__ s1q, const unsigned short* __restrict__ s2q,
    const int* __restrict__ cnt, const uint4* __restrict__ rec,
    const float* __restrict__ Wrad1, const float* __restrict__ Wmix0,
    uint2* __restrict__ pk)
{
    __shared__ float wmixT[1056];   // Wmix0 transposed, stride 33
    __shared__ float Ash[2][4][32];
    __shared__ float Bsh[2][32];
    int t = threadIdx.x;
    for (int i = t; i < 1024; i += 256) wmixT[(i & 31) * 33 + (i >> 5)] = Wmix0[i];
    int bid = XSWZ(blockIdx.x, FN / 2);
    int g = t >> 5, c = t & 31;
    int al = g >> 2, q = g & 3;
    int n = bid * 2 + al;
    h2 wr[4];
    prep_wr(Wrad1, c, wr);
    __syncthreads();

    int cn = min(cnt[n], CAP);
    int base = n * CAP;
    int j  = base + ((cn * q) >> 2);
    int j1 = base + ((cn * (q + 1)) >> 2);
    float A = 0.f;
    for (; j + 3 < j1; j += 4) {
        int n0, n1, n2, n3;
        uint4 b0, b1, b2, b3;
        LOADREC(j, n0, b0) LOADREC(j+1, n1, b1) LOADREC(j+2, n2, b2) LOADREC(j+3, n3, b3)
        A += dot8h(b0, wr) * b2f(ba1q[(n0 >> 3) * 32 + c])
           + dot8h(b1, wr) * b2f(ba1q[(n1 >> 3) * 32 + c])
           + dot8h(b2, wr) * b2f(ba1q[(n2 >> 3) * 32 + c])
           + dot8h(b3, wr) * b2f(ba1q[(n3 >> 3) * 32 + c]);
    }
    for (; j < j1; ++j) {
        int n0; uint4 b0;
        LOADREC(j, n0, b0)
        A += dot8h(b0, wr) * b2f(ba1q[(n0 >> 3) * 32 + c]);
    }
    Ash[al][q][c] = A;
    __syncthreads();
    if (q == 0) {
        float At = Ash[al][0][c] + Ash[al][1][c] + Ash[al][2][c] + Ash[al][3][c];
        int n32c = n * 32 + c;
        float bs1 = barS2[n32c] + At;
        Bsh[al][c] = bs1;
        float acc = 0.f;
#pragma unroll 8
        for (int d = 0; d < 32; d++) acc += Bsh[al][d] * wmixT[d * 33 + c];
        uint2 v;
        v.x = (unsigned)s1q[n32c] | ((unsigned)s2q[n32c] << 16);
        v.y = (unsigned)f2b(acc)  | ((unsigned)ba1q[n32c] << 16);
        pk[n32c] = v;
    }
}

// ---------------- energy reduction: 2048 per frame -> out[f] ----------------
__global__ __launch_bounds__(256) void k_ered(const float* __restrict__ epart, float* __restrict__ out)
{
    __shared__ float sm[256];
    int f = blockIdx.x, t = threadIdx.x;
    float a = 0.f;
    for (int i = t; i < N_AT; i += 256) a += epart[f * N_AT + i];
    sm[t] = a;
    __syncthreads();
    for (int s = 128; s; s >>= 1) {
        if (t < s) sm[t] += sm[t + s];
        __syncthreads();
    }
    if (t == 0) out[f] = sm[0];
}

// ---------------- forces, EDGE-PARALLEL (sequential per-edge streams, random pk rows only) ----------------
#define EPG 8   // edges per 32-lane group
__global__ __launch_bounds__(256, 8) void k_force_e(
    const uint2* __restrict__ pk, const float* __restrict__ g2,
    const uint4* __restrict__ dbq, const float4* __restrict__ unit,
    const int* __restrict__ eidx, const int* __restrict__ at,
    const float* __restrict__ W_embed, const float* __restrict__ W_rad,
    float* __restrict__ out)
{
    __shared__ float We[128];
    int t = threadIdx.x;
    if (t < 128) We[t] = W_embed[t];
    int bid = XSWZ(blockIdx.x, FE / (8 * EPG));
    int g = t >> 5;
    int c = t & 31;
    h2 wr0[4], wr1[4], wr2[4];
    prep_wr(W_rad + 0 * 1024, c, wr0);
    prep_wr(W_rad + 1 * 1024, c, wr1);
    prep_wr(W_rad + 2 * 1024, c, wr2);
    float g2c = g2[c];
    __syncthreads();

    int kbase = (bid * 8 + g) * EPG;
#pragma unroll 2
    for (int kk = 0; kk < EPG; ++kk) {
        int k = kbase + kk;
        int f = k >> 15;
        int e = k & (E_EDGE - 1);
        int a = eidx[f * 2 * E_EDGE + e] + f * N_AT;
        int b = eidx[f * 2 * E_EDGE + E_EDGE + e] + f * N_AT;
        uint4 d  = dbq[k];
        uint2 qa = pk[a * 32 + c];
        uint2 qb = pk[b * 32 + c];
        float s0a = We[at[a] * 32 + c];
        float s0b = We[at[b] * 32 + c];
        float dR0 = dot8h(d, wr0), dR1 = dot8h(d, wr1), dR2 = dot8h(d, wr2);
        float tc = dR0 * (blo(qa.y) * s0b + blo(qb.y) * s0a)
                 + dR1 * (bhi(qa.y) * blo(qb.x) + bhi(qb.y) * blo(qa.x))
                 + dR2 * g2c * (bhi(qa.x) + bhi(qb.x));
#pragma unroll
        for (int o = 1; o <= 16; o <<= 1) tc += __shfl_xor(tc, o, 32);
        float4 uv = unit[k];
        if (c < 3) {
            float uc = (c == 0) ? uv.x : (c == 1) ? uv.y : uv.z;
            atomicAdd(&out[8 + a * 3 + c], tc * uc);
        } else if (c < 6) {
            int d3 = c - 3;
            float uc = (d3 == 0) ? uv.x : (d3 == 1) ? uv.y : uv.z;
            atomicAdd(&out[8 + b * 3 + d3], -tc * uc);
        }
    }
}

extern "C" void kernel_launch(void* const* d_in, const int* in_sizes, int n_in,
                              void* d_out, int out_size, void* d_ws, size_t ws_size,
                              hipStream_t stream)
{
    const float* pos     = (const float*)d_in[0];
    const int*   eidx    = (const int*)  d_in[1];
    const float* cell    = (const float*)d_in[2];
    const int*   at      = (const int*)  d_in[3];
    const float* W_embed = (const float*)d_in[4];
    const float* W_rad   = (const float*)d_in[5];
    const float* W_mix   = (const float*)d_in[6];
    const float* w_out   = (const float*)d_in[7];
    const int*   co      = (const int*)  d_in[8];

    char* p = (char*)d_ws;
    auto carve = [&](size_t bytes) -> char* {
        char* r = p;
        p += (bytes + 255) & ~(size_t)255;
        return r;
    };
    uint4*          dbq    = (uint4*)          carve((size_t)FE * 16);
    float4*         unit   = (float4*)         carve((size_t)FE * 16);
    unsigned short* s1q    = (unsigned short*) carve((size_t)FN * 32 * 2);
    unsigned short* s2q    = (unsigned short*) carve((size_t)FN * 32 * 2);
    unsigned short* ba1q   = (unsigned short*) carve((size_t)FN * 32 * 2);
    float*          barS2  = (float*)          carve((size_t)FN * 32 * 4);
    uint2*          pk     = (uint2*)          carve((size_t)FN * 32 * 8);
    float*          g2     = (float*)          carve(32 * 4);
    float*          epart  = (float*)          carve((size_t)FN * 4);
    int*            cnt    = (int*)            carve((size_t)FN * 4);
    uint4*          rec    = (uint4*)          carve((size_t)FN * CAP * 32);

    hipMemsetAsync(cnt, 0, (size_t)FN * 4, stream);
    hipMemsetAsync(d_out, 0, (size_t)(8 + FN * 3) * 4, stream);  // energy + force accumulators

    k_edges<<<FE / 256, 256, 0, stream>>>(pos, eidx, cell, co, at, dbq, unit, cnt, rec);
    k_g2<<<1, 32, 0, stream>>>(w_out, W_mix + 2 * 1024, g2);

    // forward
    k_L<true><<<FN / 2, 256, 0, stream>>>(nullptr, W_embed, s1q, cnt, rec,
                                          W_rad + 0 * 1024, W_mix + 0 * 1024, at);
    k_L<false><<<FN / 2, 256, 0, stream>>>(s1q, W_embed, s2q, cnt, rec,
                                           W_rad + 1 * 1024, W_mix + 1 * 1024, at);
    // layer 2 + energy partials + barS2 + barA1
    k_L2E<<<FN / 2, 256, 0, stream>>>(s2q, cnt, rec, W_rad + 2 * 1024,
                                      W_mix + 1 * 1024, w_out, g2, barS2, ba1q, epart);
    // backward l=1 + barA0 + pack
    k_B1F<<<FN / 2, 256, 0, stream>>>(ba1q, barS2, s1q, s2q, cnt, rec,
                                      W_rad + 1 * 1024, W_mix + 0 * 1024, pk);
    // energy reduce
    k_ered<<<F_NUM, 256, 0, stream>>>(epart, (float*)d_out);
    // forces (edge-parallel, atomic accumulation)
    k_force_e<<<FE / (8 * EPG), 256, 0, stream>>>(pk, g2, dbq, unit, eidx, at, W_embed, W_rad, (float*)d_out);
}

// Round 11
// 221.392 us; speedup vs baseline: 1.3043x; 1.0294x over previous
//
#include <hip/hip_runtime.h>
#include <math.h>

#define F_NUM 8
#define N_AT 2048
#define E_EDGE 32768
#define FE (F_NUM*E_EDGE)   // 262144 base edges
#define FN (F_NUM*N_AT)     // 16384 atoms
#define CAP 72              // per-atom incidence capacity (avg 32, Poisson)
#define PI_F 3.14159265358979f

#if defined(__has_builtin)
#if __has_builtin(__builtin_amdgcn_fdot2)
#define HAS_FDOT2 1
#endif
#endif

typedef _Float16 h2 __attribute__((ext_vector_type(2)));

// XCD-aware swizzle: frame-major work chunks land on one XCD (frame f -> XCD f)
#define XSWZ(bid, G) (((bid) & 7) * ((G) >> 3) + ((bid) >> 3))

__device__ __forceinline__ unsigned short f2b(float x) {
    unsigned int u = __float_as_uint(x);
    u += 0x8000u;
    return (unsigned short)(u >> 16);
}
__device__ __forceinline__ float blo(unsigned int u) { return __uint_as_float(u << 16); }
__device__ __forceinline__ float bhi(unsigned int u) { return __uint_as_float(u & 0xffff0000u); }
__device__ __forceinline__ float b2f(unsigned short u) { return __uint_as_float((unsigned)u << 16); }

__device__ __forceinline__ unsigned f2h(float x) {
    union { _Float16 h; unsigned short u; } cv;
    cv.h = (_Float16)x;
    return (unsigned)cv.u;
}
__device__ __forceinline__ h2 u2h2(unsigned u) {
    union { unsigned u; h2 h; } cv;
    cv.u = u;
    return cv.h;
}
__device__ __forceinline__ float dot8h(uint4 q, const h2* w) {
#ifdef HAS_FDOT2
    float a = __builtin_amdgcn_fdot2(u2h2(q.x), w[0], 0.f, false);
    a = __builtin_amdgcn_fdot2(u2h2(q.y), w[1], a, false);
    a = __builtin_amdgcn_fdot2(u2h2(q.z), w[2], a, false);
    a = __builtin_amdgcn_fdot2(u2h2(q.w), w[3], a, false);
    return a;
#else
    h2 a0 = u2h2(q.x), a1 = u2h2(q.y), a2 = u2h2(q.z), a3 = u2h2(q.w);
    return (float)a0.x*(float)w[0].x + (float)a0.y*(float)w[0].y
         + (float)a1.x*(float)w[1].x + (float)a1.y*(float)w[1].y
         + (float)a2.x*(float)w[2].x + (float)a2.y*(float)w[2].y
         + (float)a3.x*(float)w[3].x + (float)a3.y*(float)w[3].y;
#endif
}
__device__ __forceinline__ void prep_wr(const float* __restrict__ Wrad_l, int c, h2* wr) {
#pragma unroll
    for (int bb = 0; bb < 4; bb++) {
        h2 t;
        t.x = (_Float16)Wrad_l[(2*bb)   * 128 + c * 4];
        t.y = (_Float16)Wrad_l[(2*bb+1) * 128 + c * 4];
        wr[bb] = t;
    }
}

// Incidence record (32 B, one cache line per write):
//   rec[2j]   = { nb, B.x, B.y, B.z }    nb = (u<<3)|(sign<<2)|type
//   rec[2j+1] = { B.w, (k<<1)|sign, 0, 0 }   k = edge id (for force gather)

// ---------------- edges: geometry, f16 dbasis+unit (edge order), AoS incidence records ----------------
__global__ __launch_bounds__(256) void k_edges(
    const float* __restrict__ pos, const int* __restrict__ eidx,
    const float* __restrict__ cell, const int* __restrict__ co_p,
    const int* __restrict__ at,
    uint4* __restrict__ dbq, float4* __restrict__ unit,
    int* __restrict__ cnt, uint4* __restrict__ rec)
{
    int bid = XSWZ(blockIdx.x, FE / 256);
    int k = bid * 256 + threadIdx.x;
    int f = k >> 15;
    int e = k & (E_EDGE - 1);
    int a = eidx[f * 2 * E_EDGE + e] + f * N_AT;
    int b = eidx[f * 2 * E_EDGE + E_EDGE + e] + f * N_AT;
    int ta = at[a], tb = at[b];
    float co = (float)co_p[0];

    float vec[3];
#pragma unroll
    for (int d = 0; d < 3; d++) {
        float v  = pos[3 * b + d] - pos[3 * a + d];
        float cl = cell[3 * f + d];
        float sh = cl * ((v < -co ? 1.f : 0.f) - (v > co ? 1.f : 0.f));
        vec[d] = v + sh;
    }
    float r2   = vec[0]*vec[0] + vec[1]*vec[1] + vec[2]*vec[2] + 1e-12f;
    float r    = sqrtf(r2);
    float rinv = 1.f / r;
    unit[k] = make_float4(vec[0]*rinv, vec[1]*rinv, vec[2]*rinv, 0.f);

    float x = r * (1.f / 6.f);           // R_MAX = 6
    float env = 0.f, denv = 0.f;
    if (x < 1.f) {
        float x2 = x*x, x3 = x2*x, x5 = x2*x3, x6 = x5*x, x7 = x6*x, x8 = x7*x;
        env  = 1.f - 28.f*x6 + 48.f*x7 - 21.f*x8;
        denv = -168.f*x5 + 336.f*x6 - 168.f*x7;
    }
    float s1, c1;
    sincosf(PI_F * x, &s1, &c1);
    float sn = s1, cn = c1;
    const float C0 = 0.57735026919f;     // sqrt(2/6)
    float bs[8], db[8];
#pragma unroll
    for (int n = 1; n <= 8; n++) {
        float kn  = (float)n * PI_F * (1.f / 6.f);
        float bes = C0 * sn * rinv;
        bs[n-1] = bes * env;
        db[n-1] = C0 * rinv * (kn * cn - sn * rinv) * env + bes * denv * (1.f / 6.f);
        float sn2 = sn * c1 + cn * s1;
        float cn2 = cn * c1 - sn * s1;
        sn = sn2; cn = cn2;
    }
    uint4 B, D;
    B.x = f2h(bs[0]) | (f2h(bs[1]) << 16);
    B.y = f2h(bs[2]) | (f2h(bs[3]) << 16);
    B.z = f2h(bs[4]) | (f2h(bs[5]) << 16);
    B.w = f2h(bs[6]) | (f2h(bs[7]) << 16);
    D.x = f2h(db[0]) | (f2h(db[1]) << 16);
    D.y = f2h(db[2]) | (f2h(db[3]) << 16);
    D.z = f2h(db[4]) | (f2h(db[5]) << 16);
    D.w = f2h(db[6]) | (f2h(db[7]) << 16);
    dbq[k] = D;

    int sa = atomicAdd(&cnt[a], 1);
    if (sa < CAP) {
        int ia = 2 * (a * CAP + sa);
        rec[ia]     = make_uint4((unsigned)((b << 3) | tb), B.x, B.y, B.z);
        rec[ia + 1] = make_uint4(B.w, (unsigned)(k << 1), 0, 0);
    }
    int sb = atomicAdd(&cnt[b], 1);
    if (sb < CAP) {
        int ib = 2 * (b * CAP + sb);
        rec[ib]     = make_uint4((unsigned)((a << 3) | 4 | ta), B.x, B.y, B.z);
        rec[ib + 1] = make_uint4(B.w, (unsigned)((k << 1) | 1), 0, 0);
    }
}

// ---------------- g2[c] = sum_d w_out[d] * Wmix2[c,d] ----------------
__global__ void k_g2(const float* __restrict__ w_out, const float* __restrict__ Wmix2, float* __restrict__ g2)
{
    int c = threadIdx.x;
    float acc = 0.f;
#pragma unroll
    for (int d = 0; d < 32; d++) acc += w_out[d] * Wmix2[c * 32 + d];
    g2[c] = acc;
}

#define LOADREC(J, NB, B)                                    \
    {                                                        \
        uint4 ra = rec[2*(J)], rb = rec[2*(J)+1];            \
        NB = (int)ra.x;                                      \
        B  = make_uint4(ra.y, ra.z, ra.w, rb.x);             \
    }

// ---------------- forward layer: 2 atoms/block, 4 groups/atom ----------------
template<bool L0>
__global__ __launch_bounds__(256, 8) void k_L(
    const unsigned short* __restrict__ slq, const float* __restrict__ W_embed,
    unsigned short* __restrict__ soq,
    const int* __restrict__ cnt, const uint4* __restrict__ rec,
    const float* __restrict__ Wrad_l, const float* __restrict__ Wmix_l,
    const int* __restrict__ at)
{
    __shared__ float wmix[1024];
    __shared__ float Ash[2][4][32];
    __shared__ float We[128];
    int t = threadIdx.x;
    for (int i = t; i < 1024; i += 256) wmix[i] = Wmix_l[i];
    if (L0 && t < 128) We[t] = W_embed[t];
    int bid = XSWZ(blockIdx.x, FN / 2);
    int g = t >> 5, c = t & 31;
    int al = g >> 2, q = g & 3;
    int n = bid * 2 + al;
    h2 wr[4];
    prep_wr(Wrad_l, c, wr);
    __syncthreads();

    int cn = min(cnt[n], CAP);
    int base = n * CAP;
    int j  = base + ((cn * q) >> 2);
    int j1 = base + ((cn * (q + 1)) >> 2);
    float A = 0.f;
    for (; j + 3 < j1; j += 4) {
        int n0, n1, n2, n3;
        uint4 b0, b1, b2, b3;
        LOADREC(j, n0, b0) LOADREC(j+1, n1, b1) LOADREC(j+2, n2, b2) LOADREC(j+3, n3, b3)
        float sv0, sv1, sv2, sv3;
        if (L0) {
            sv0 = We[(n0 & 3) * 32 + c];
            sv1 = We[(n1 & 3) * 32 + c];
            sv2 = We[(n2 & 3) * 32 + c];
            sv3 = We[(n3 & 3) * 32 + c];
        } else {
            sv0 = b2f(slq[(n0 >> 3) * 32 + c]);
            sv1 = b2f(slq[(n1 >> 3) * 32 + c]);
            sv2 = b2f(slq[(n2 >> 3) * 32 + c]);
            sv3 = b2f(slq[(n3 >> 3) * 32 + c]);
        }
        A += dot8h(b0, wr) * sv0 + dot8h(b1, wr) * sv1
           + dot8h(b2, wr) * sv2 + dot8h(b3, wr) * sv3;
    }
    for (; j < j1; ++j) {
        int n0; uint4 b0;
        LOADREC(j, n0, b0)
        float sv0 = L0 ? We[(n0 & 3) * 32 + c] : b2f(slq[(n0 >> 3) * 32 + c]);
        A += dot8h(b0, wr) * sv0;
    }
    Ash[al][q][c] = A;
    __syncthreads();
    if (q == 0) {
        float acc = 0.f;
#pragma unroll 8
        for (int cc = 0; cc < 32; cc++) {
            float Av = Ash[al][0][cc] + Ash[al][1][cc] + Ash[al][2][cc] + Ash[al][3][cc];
            acc += Av * wmix[cc * 32 + c];
        }
        float base_s = L0 ? We[at[n] * 32 + c] : b2f(slq[n * 32 + c]);
        soq[n * 32 + c] = f2b(base_s + acc);
    }
}

// ---------------- layer 2 fused: energy partial + barS2 + barA1(bf16) ----------------
__global__ __launch_bounds__(256, 8) void k_L2E(
    const unsigned short* __restrict__ s2q,
    const int* __restrict__ cnt, const uint4* __restrict__ rec,
    const float* __restrict__ Wrad2, const float* __restrict__ Wmix1,
    const float* __restrict__ w_out, const float* __restrict__ g2,
    float* __restrict__ barS2, unsigned short* __restrict__ ba1q, float* __restrict__ epart)
{
    __shared__ float wmixT[1056];   // Wmix1 transposed, stride 33
    __shared__ float Ash[2][4][32];
    __shared__ float Ssh[2][4][32];
    __shared__ float Bsh[2][32];
    int t = threadIdx.x;
    for (int i = t; i < 1024; i += 256) wmixT[(i & 31) * 33 + (i >> 5)] = Wmix1[i];
    int bid = XSWZ(blockIdx.x, FN / 2);
    int g = t >> 5, c = t & 31;
    int al = g >> 2, q = g & 3;
    int n = bid * 2 + al;
    h2 wr[4];
    prep_wr(Wrad2, c, wr);
    __syncthreads();

    int cn = min(cnt[n], CAP);
    int base = n * CAP;
    int j  = base + ((cn * q) >> 2);
    int j1 = base + ((cn * (q + 1)) >> 2);
    float A = 0.f, S = 0.f;
    for (; j + 3 < j1; j += 4) {
        int n0, n1, n2, n3;
        uint4 b0, b1, b2, b3;
        LOADREC(j, n0, b0) LOADREC(j+1, n1, b1) LOADREC(j+2, n2, b2) LOADREC(j+3, n3, b3)
        float r0 = dot8h(b0, wr), r1 = dot8h(b1, wr), r2 = dot8h(b2, wr), r3 = dot8h(b3, wr);
        A += r0 * b2f(s2q[(n0 >> 3) * 32 + c]) + r1 * b2f(s2q[(n1 >> 3) * 32 + c])
           + r2 * b2f(s2q[(n2 >> 3) * 32 + c]) + r3 * b2f(s2q[(n3 >> 3) * 32 + c]);
        S += r0 + r1 + r2 + r3;
    }
    for (; j < j1; ++j) {
        int n0; uint4 b0;
        LOADREC(j, n0, b0)
        float r0 = dot8h(b0, wr);
        A += r0 * b2f(s2q[(n0 >> 3) * 32 + c]);
        S += r0;
    }
    Ash[al][q][c] = A;
    Ssh[al][q][c] = S;
    __syncthreads();
    if (q == 0) {
        float At = Ash[al][0][c] + Ash[al][1][c] + Ash[al][2][c] + Ash[al][3][c];
        float St = Ssh[al][0][c] + Ssh[al][1][c] + Ssh[al][2][c] + Ssh[al][3][c];
        float woc = w_out[c], g2c = g2[c];
        float s2n = b2f(s2q[n * 32 + c]);
        float te = s2n * woc + At * g2c;
#pragma unroll
        for (int o = 1; o <= 16; o <<= 1) te += __shfl_xor(te, o, 32);
        if (c == 0) epart[n] = te;
        float bs2 = woc + g2c * St;
        barS2[n * 32 + c] = bs2;
        Bsh[al][c] = bs2;
        float acc = 0.f;
#pragma unroll 8
        for (int d = 0; d < 32; d++) acc += Bsh[al][d] * wmixT[d * 33 + c];
        ba1q[n * 32 + c] = f2b(acc);
    }
}

// ---------------- backward l=1 fused: barS1 -> barA0 -> pk ----------------
// pk layout: x = s1 | s2<<16 ; y = ba0 | ba1<<16
__global__ __launch_bounds__(256, 8) void k_B1F(
    const unsigned short* __restrict__ ba1q, const float* __restrict__ barS2,
    const unsigned short* __restrict__ s1q, const unsigned short* __restrict__ s2q,
    const int* __restrict__ cnt, const uint4* __restrict__ rec,
    const float* __restrict__ Wrad1, const float* __restrict__ Wmix0,
    uint2* __restrict__ pk)
{
    __shared__ float wmixT[1056];   // Wmix0 transposed, stride 33
    __shared__ float Ash[2][4][32];
    __shared__ float Bsh[2][32];
    int t = threadIdx.x;
    for (int i = t; i < 1024; i += 256) wmixT[(i & 31) * 33 + (i >> 5)] = Wmix0[i];
    int bid = XSWZ(blockIdx.x, FN / 2);
    int g = t >> 5, c = t & 31;
    int al = g >> 2, q = g & 3;
    int n = bid * 2 + al;
    h2 wr[4];
    prep_wr(Wrad1, c, wr);
    __syncthreads();

    int cn = min(cnt[n], CAP);
    int base = n * CAP;
    int j  = base + ((cn * q) >> 2);
    int j1 = base + ((cn * (q + 1)) >> 2);
    float A = 0.f;
    for (; j + 3 < j1; j += 4) {
        int n0, n1, n2, n3;
        uint4 b0, b1, b2, b3;
        LOADREC(j, n0, b0) LOADREC(j+1, n1, b1) LOADREC(j+2, n2, b2) LOADREC(j+3, n3, b3)
        A += dot8h(b0, wr) * b2f(ba1q[(n0 >> 3) * 32 + c])
           + dot8h(b1, wr) * b2f(ba1q[(n1 >> 3) * 32 + c])
           + dot8h(b2, wr) * b2f(ba1q[(n2 >> 3) * 32 + c])
           + dot8h(b3, wr) * b2f(ba1q[(n3 >> 3) * 32 + c]);
    }
    for (; j < j1; ++j) {
        int n0; uint4 b0;
        LOADREC(j, n0, b0)
        A += dot8h(b0, wr) * b2f(ba1q[(n0 >> 3) * 32 + c]);
    }
    Ash[al][q][c] = A;
    __syncthreads();
    if (q == 0) {
        float At = Ash[al][0][c] + Ash[al][1][c] + Ash[al][2][c] + Ash[al][3][c];
        int n32c = n * 32 + c;
        float bs1 = barS2[n32c] + At;
        Bsh[al][c] = bs1;
        float acc = 0.f;
#pragma unroll 8
        for (int d = 0; d < 32; d++) acc += Bsh[al][d] * wmixT[d * 33 + c];
        uint2 v;
        v.x = (unsigned)s1q[n32c] | ((unsigned)s2q[n32c] << 16);
        v.y = (unsigned)f2b(acc)  | ((unsigned)ba1q[n32c] << 16);
        pk[n32c] = v;
    }
}

// ---------------- energy reduction: 2048 per frame -> out[f] ----------------
__global__ __launch_bounds__(256) void k_ered(const float* __restrict__ epart, float* __restrict__ out)
{
    __shared__ float sm[256];
    int f = blockIdx.x, t = threadIdx.x;
    float a = 0.f;
    for (int i = t; i < N_AT; i += 256) a += epart[f * N_AT + i];
    sm[t] = a;
    __syncthreads();
    for (int s = 128; s; s >>= 1) {
        if (t < s) sm[t] += sm[t + s];
        __syncthreads();
    }
    if (t == 0) out[f] = sm[0];
}

// ---------------- force pass 1, EDGE-PARALLEL: per-edge scalar dEdr, plain store ----------------
#define EPG 8   // edges per 32-lane group
__global__ __launch_bounds__(256, 8) void k_force_e(
    const uint2* __restrict__ pk, const float* __restrict__ g2,
    const uint4* __restrict__ dbq,
    const int* __restrict__ eidx, const int* __restrict__ at,
    const float* __restrict__ W_embed, const float* __restrict__ W_rad,
    float* __restrict__ dEdr)
{
    __shared__ float We[128];
    int t = threadIdx.x;
    if (t < 128) We[t] = W_embed[t];
    int bid = XSWZ(blockIdx.x, FE / (8 * EPG));
    int g = t >> 5;
    int c = t & 31;
    h2 wr0[4], wr1[4], wr2[4];
    prep_wr(W_rad + 0 * 1024, c, wr0);
    prep_wr(W_rad + 1 * 1024, c, wr1);
    prep_wr(W_rad + 2 * 1024, c, wr2);
    float g2c = g2[c];
    __syncthreads();

    int kbase = (bid * 8 + g) * EPG;
#pragma unroll 2
    for (int kk = 0; kk < EPG; ++kk) {
        int k = kbase + kk;
        int f = k >> 15;
        int e = k & (E_EDGE - 1);
        int a = eidx[f * 2 * E_EDGE + e] + f * N_AT;
        int b = eidx[f * 2 * E_EDGE + E_EDGE + e] + f * N_AT;
        uint4 d  = dbq[k];
        uint2 qa = pk[a * 32 + c];
        uint2 qb = pk[b * 32 + c];
        float s0a = We[at[a] * 32 + c];
        float s0b = We[at[b] * 32 + c];
        float dR0 = dot8h(d, wr0), dR1 = dot8h(d, wr1), dR2 = dot8h(d, wr2);
        float tc = dR0 * (blo(qa.y) * s0b + blo(qb.y) * s0a)
                 + dR1 * (bhi(qa.y) * blo(qb.x) + bhi(qb.y) * blo(qa.x))
                 + dR2 * g2c * (bhi(qa.x) + bhi(qb.x));
#pragma unroll
        for (int o = 1; o <= 16; o <<= 1) tc += __shfl_xor(tc, o, 32);
        if (c == 0) dEdr[k] = tc;
    }
}

// ---------------- force pass 2: per-atom gather of dEdr*unit (lanes = visits, zero atomics) ----------------
__global__ __launch_bounds__(256, 8) void k_fgat(
    const int* __restrict__ cnt, const uint4* __restrict__ rec,
    const float* __restrict__ dEdr, const float4* __restrict__ unit,
    float* __restrict__ out)
{
    int t = threadIdx.x;
    int bid = XSWZ(blockIdx.x, FN / 8);
    int g = t >> 5, lane = t & 31;
    int n = bid * 8 + g;
    int cn = min(cnt[n], CAP);
    int base = n * CAP;
    float Fx = 0.f, Fy = 0.f, Fz = 0.f;
    for (int j = base + lane; j < base + cn; j += 32) {
        unsigned s = rec[2 * j + 1].y;
        int k = (int)(s >> 1);
        float sg = (s & 1) ? -1.f : 1.f;
        float4 uv = unit[k];
        float d = dEdr[k] * sg;
        Fx += d * uv.x; Fy += d * uv.y; Fz += d * uv.z;
    }
#pragma unroll
    for (int o = 1; o <= 16; o <<= 1) {
        Fx += __shfl_xor(Fx, o, 32);
        Fy += __shfl_xor(Fy, o, 32);
        Fz += __shfl_xor(Fz, o, 32);
    }
    if (lane == 0) {
        out[8 + n * 3 + 0] = Fx;
        out[8 + n * 3 + 1] = Fy;
        out[8 + n * 3 + 2] = Fz;
    }
}

extern "C" void kernel_launch(void* const* d_in, const int* in_sizes, int n_in,
                              void* d_out, int out_size, void* d_ws, size_t ws_size,
                              hipStream_t stream)
{
    const float* pos     = (const float*)d_in[0];
    const int*   eidx    = (const int*)  d_in[1];
    const float* cell    = (const float*)d_in[2];
    const int*   at      = (const int*)  d_in[3];
    const float* W_embed = (const float*)d_in[4];
    const float* W_rad   = (const float*)d_in[5];
    const float* W_mix   = (const float*)d_in[6];
    const float* w_out   = (const float*)d_in[7];
    const int*   co      = (const int*)  d_in[8];

    char* p = (char*)d_ws;
    auto carve = [&](size_t bytes) -> char* {
        char* r = p;
        p += (bytes + 255) & ~(size_t)255;
        return r;
    };
    uint4*          dbq    = (uint4*)          carve((size_t)FE * 16);
    float4*         unit   = (float4*)         carve((size_t)FE * 16);
    unsigned short* s1q    = (unsigned short*) carve((size_t)FN * 32 * 2);
    unsigned short* s2q    = (unsigned short*) carve((size_t)FN * 32 * 2);
    unsigned short* ba1q   = (unsigned short*) carve((size_t)FN * 32 * 2);
    float*          barS2  = (float*)          carve((size_t)FN * 32 * 4);
    uint2*          pk     = (uint2*)          carve((size_t)FN * 32 * 8);
    float*          g2     = (float*)          carve(32 * 4);
    float*          epart  = (float*)          carve((size_t)FN * 4);
    float*          dEdr   = (float*)          carve((size_t)FE * 4);
    int*            cnt    = (int*)            carve((size_t)FN * 4);
    uint4*          rec    = (uint4*)          carve((size_t)FN * CAP * 32);

    hipMemsetAsync(cnt, 0, (size_t)FN * 4, stream);

    k_edges<<<FE / 256, 256, 0, stream>>>(pos, eidx, cell, co, at, dbq, unit, cnt, rec);
    k_g2<<<1, 32, 0, stream>>>(w_out, W_mix + 2 * 1024, g2);

    // forward
    k_L<true><<<FN / 2, 256, 0, stream>>>(nullptr, W_embed, s1q, cnt, rec,
                                          W_rad + 0 * 1024, W_mix + 0 * 1024, at);
    k_L<false><<<FN / 2, 256, 0, stream>>>(s1q, W_embed, s2q, cnt, rec,
                                           W_rad + 1 * 1024, W_mix + 1 * 1024, at);
    // layer 2 + energy partials + barS2 + barA1
    k_L2E<<<FN / 2, 256, 0, stream>>>(s2q, cnt, rec, W_rad + 2 * 1024,
                                      W_mix + 1 * 1024, w_out, g2, barS2, ba1q, epart);
    // backward l=1 + barA0 + pack
    k_B1F<<<FN / 2, 256, 0, stream>>>(ba1q, barS2, s1q, s2q, cnt, rec,
                                      W_rad + 1 * 1024, W_mix + 0 * 1024, pk);
    // energy reduce (plain stores)
    k_ered<<<F_NUM, 256, 0, stream>>>(epart, (float*)d_out);
    // forces: pass 1 per-edge scalar, pass 2 per-atom gather (no atomics anywhere)
    k_force_e<<<FE / (8 * EPG), 256, 0, stream>>>(pk, g2, dbq, eidx, at, W_embed, W_rad, dEdr);
    k_fgat<<<FN / 8, 256, 0, stream>>>(cnt, rec, dEdr, unit, (float*)d_out);
}